// Round 14
// baseline (122.451 us; speedup 1.0000x reference)
//
#include <hip/hip_runtime.h>
#include <math.h>

// EdgeConditionedConv on MI355X — round 13: T4 counted-vmcnt pipeline.
// r12's per-j vmcnt(0)+__syncthreads = textbook 2-phase drain ceiling
// (MfmaUtil 28%). Now: issue j+1 loads -> s_waitcnt vmcnt(2) (j+1 stays in
// flight ACROSS the barrier) -> raw s_barrier -> compute -> raw s_barrier.
// No vmcnt(0) in the main loop. prep/gru = r9 (proven), ws layout = r5/r9.

constexpr int N_NODES  = 25000;
constexpr int N_EDGES  = 50000;
constexpr int NODE_DIM = 64;
constexpr int EDGE_DIM = 16;
constexpr int HID      = 128;
constexpr int BE       = 128;          // edges per edge_msg block

typedef __attribute__((ext_vector_type(8))) _Float16 half8;
typedef __attribute__((ext_vector_type(4))) float    f32x4;

constexpr int G_MS  = 128;             // agg-zero blocks
constexpr int G_PK  = 355;             // prepack blocks
constexpr int G_MLP = N_EDGES / 8;     // mlp1 blocks (8 edges each)

__device__ inline void gload_lds16(const void* g, void* l) {
    __builtin_amdgcn_global_load_lds(
        (const __attribute__((address_space(1))) unsigned int*)g,
        (__attribute__((address_space(3))) unsigned int*)l, 16, 0, 0);
}

// ---------------------------------------------------------------- prep
__global__ __launch_bounds__(256) void prep_kernel(
    const float* __restrict__ W2, const float* __restrict__ b2,
    const float* __restrict__ w_ih, const float* __restrict__ w_hh,
    const float* __restrict__ edge_attr, const float* __restrict__ W1,
    const float* __restrict__ b1,
    _Float16* __restrict__ Wpk, _Float16* __restrict__ b2pk,
    float* __restrict__ wTih, float* __restrict__ wThh,
    _Float16* __restrict__ h, float* __restrict__ agg)
{
    int b = blockIdx.x;
    if (b < G_MS) {
        float4* a4 = (float4*)agg;
        const float4 z = make_float4(0.f, 0.f, 0.f, 0.f);
        for (int i = b * 256 + threadIdx.x; i < N_NODES * NODE_DIM / 4; i += G_MS * 256)
            a4[i] = z;
        return;
    }
    if (b < G_MS + G_PK) {
        int c = (b - G_MS) * 256 + threadIdx.x;
        if (c < 65536) {
            int lane = c & 63, mt = (c >> 6) & 3, ks = (c >> 8) & 3, j = c >> 10;
            int i   = mt * 16 + (lane & 15);
            int col = ks * 32 + ((lane >> 4) & 3) * 8;
            const float* src = W2 + (size_t)(i * 64 + j) * HID + col;
            half8 o;
#pragma unroll
            for (int q = 0; q < 8; ++q) o[q] = (_Float16)src[q];
            ((half8*)Wpk)[c] = o;
        } else if (c < 65536 + 512) {
            int c2 = c - 65536;
            int lane = c2 & 63, mt = (c2 >> 6) & 3, ks2 = (c2 >> 8) & 1;
            int i = mt * 16 + (lane & 15);
            int j = ks2 * 32 + ((lane >> 4) & 3) * 8;
            const float* src = b2 + i * 64 + j;
            half8 o;
#pragma unroll
            for (int q = 0; q < 8; ++q) o[q] = (_Float16)src[q];
            ((half8*)b2pk)[c2] = o;
        } else if (c < 65536 + 512 + 2 * 12288) {
            int idx = c - (65536 + 512);
            const float* src = (idx < 12288) ? w_ih : w_hh;
            float*       dst = (idx < 12288) ? wTih : wThh;
            int e2 = (idx < 12288) ? idx : idx - 12288;
            int k = e2 / 192, g = e2 - k * 192;
            dst[k * 192 + g] = src[(size_t)g * 64 + k];
        }
        return;
    }
    // mlp1: 8 edges per block
    int ebase = (b - G_MS - G_PK) * 8;
    int k = threadIdx.x & 127;
    const float* w = W1 + (size_t)k * EDGE_DIM;
#pragma unroll
    for (int p = 0; p < 4; ++p) {
        int e = ebase + p * 2 + (threadIdx.x >> 7);
        if (e >= N_EDGES) break;
        const float* ea = edge_attr + (size_t)e * EDGE_DIM;
        float acc = b1[k];
#pragma unroll
        for (int d = 0; d < EDGE_DIM; ++d) acc += ea[d] * w[d];
        float g = 0.5f * acc * (1.0f + erff(acc * 0.70710678118654752f));
        h[(size_t)e * HID + k] = (_Float16)g;
    }
}

// ---------------------------------------------------------------- phase 2
// 8 waves: wave = (eh, mt). A j-slice (16 KB) double-buffered in LDS via
// global_load_lds; counted vmcnt keeps next slice in flight across barriers.
__global__ __launch_bounds__(512, 2) void edge_msg_mfma_kernel(
    const _Float16* __restrict__ hbuf,
    const float*    __restrict__ x,
    const int*      __restrict__ edge_index,   // [2][E] int32
    const _Float16* __restrict__ Wpk,
    const _Float16* __restrict__ b2pk,
    float* __restrict__ agg)                   // [N][64], pre-zeroed
{
    __shared__ __align__(16) char Asl[2][16384];   // A j-slice double buffer
    __shared__ float xsh[BE * 68];                 // gathered x[src], pitch 68
    __shared__ int   dsts[BE];
    float* msgred = xsh;                           // alias: [i][e] 64 x 130

    const int e0   = blockIdx.x * BE;
    const int t    = threadIdx.x;
    const int wave = t >> 6;
    const int lane = t & 63;
    const int mt   = wave & 3;          // i-row block
    const int eh   = wave >> 2;         // edge half

    // ---- gather x[src[e]] rows into xsh (zero-fill invalid) + dsts
    if (t < BE) dsts[t] = (e0 + t < N_EDGES) ? edge_index[N_EDGES + e0 + t] : -1;
#pragma unroll
    for (int r = 0; r < 4; ++r) {
        int idx = t + r * 512;            // 0..2047 float4 slots
        int le = idx >> 4, q = idx & 15;
        int e = e0 + le;
        float4 v = make_float4(0.f, 0.f, 0.f, 0.f);
        if (e < N_EDGES) {
            int s = edge_index[e];
            if ((unsigned)s < (unsigned)N_NODES)
                v = ((const float4*)x)[(size_t)s * 16 + q];
        }
        *(float4*)&xsh[le * 68 + q * 4] = v;
    }

    // ---- per-wave resident h fragments for this eh half
    half8 hf[4][4];   // [nt][ks]
#pragma unroll
    for (int nt = 0; nt < 4; ++nt) {
#pragma unroll
        for (int ks = 0; ks < 4; ++ks) {
            int el = eh * 64 + nt * 16 + (lane & 15);
            int ee = e0 + el; if (ee >= N_EDGES) ee = N_EDGES - 1;
            int gk = ks * 32 + ((lane >> 4) & 3) * 8;
            hf[nt][ks] = *(const half8*)(hbuf + (size_t)ee * HID + gk);
        }
    }

    // ---- stage j=0 slice; single full drain + sync (prologue only)
    {
        const _Float16* gsrc = Wpk + ((size_t)0 * 1024 + wave * 128) * 8;
        char* lb = &Asl[0][wave * 2048];
        gload_lds16(gsrc + (size_t)lane * 8, lb);
        gload_lds16(gsrc + (size_t)(64 + lane) * 8, lb + 1024);
    }
    asm volatile("s_waitcnt vmcnt(0)" ::: "memory");
    __syncthreads();

    const f32x4 zero4 = {0.f, 0.f, 0.f, 0.f};
    f32x4 msg[4];
#pragma unroll
    for (int nt = 0; nt < 4; ++nt) msg[nt] = zero4;

    auto computeJ = [&](int j, int cur) {
        float gv[4];
#pragma unroll
        for (int nt = 0; nt < 4; ++nt)
            gv[nt] = xsh[(eh * 64 + nt * 16 + (lane & 15)) * 68 + j];
        const half8* As = (const half8*)&Asl[cur][0];
        f32x4 P[4];
#pragma unroll
        for (int ks = 0; ks < 4; ++ks) {
            half8 av = As[ks * 256 + mt * 64 + lane];
#pragma unroll
            for (int nt = 0; nt < 4; ++nt)
                P[nt] = __builtin_amdgcn_mfma_f32_16x16x32_f16(
                    av, hf[nt][ks], ks == 0 ? zero4 : P[nt], 0, 0, 0);
        }
#pragma unroll
        for (int nt = 0; nt < 4; ++nt)
#pragma unroll
            for (int r = 0; r < 4; ++r) msg[nt][r] += gv[nt] * P[nt][r];
    };

    int cur = 0;
#pragma unroll 1
    for (int j = 0; j < 63; ++j) {
        // issue next slice (rides across the barriers, never drained here)
        {
            const _Float16* gsrc = Wpk + ((size_t)(j + 1) * 1024 + wave * 128) * 8;
            char* lb = &Asl[cur ^ 1][wave * 2048];
            gload_lds16(gsrc + (size_t)lane * 8, lb);
            gload_lds16(gsrc + (size_t)(64 + lane) * 8, lb + 1024);
        }
        asm volatile("s_waitcnt vmcnt(2)" ::: "memory");   // j landed; j+1 in flight
        __builtin_amdgcn_s_barrier();
        __builtin_amdgcn_sched_barrier(0);
        computeJ(j, cur);
        __builtin_amdgcn_sched_barrier(0);
        __builtin_amdgcn_s_barrier();                      // buf reuse fence
        cur ^= 1;
    }
    asm volatile("s_waitcnt vmcnt(0)" ::: "memory");       // last slice
    __builtin_amdgcn_s_barrier();
    __builtin_amdgcn_sched_barrier(0);
    computeJ(63, cur);

    // ---- bias: msg[i,e] += sum_j b2[i*64+j]*g[e,j]  (this wave's tile)
#pragma unroll
    for (int ks2 = 0; ks2 < 2; ++ks2) {
        half8 gf[4];
#pragma unroll
        for (int nt = 0; nt < 4; ++nt) {
            const float* gp = &xsh[(eh * 64 + nt * 16 + (lane & 15)) * 68 + ks2 * 32 + ((lane >> 4) & 3) * 8];
            float4 lo = *(const float4*)gp;
            float4 hi = *(const float4*)(gp + 4);
            half8 g8;
            g8[0] = (_Float16)lo.x; g8[1] = (_Float16)lo.y;
            g8[2] = (_Float16)lo.z; g8[3] = (_Float16)lo.w;
            g8[4] = (_Float16)hi.x; g8[5] = (_Float16)hi.y;
            g8[6] = (_Float16)hi.z; g8[7] = (_Float16)hi.w;
            gf[nt] = g8;
        }
        half8 bf8 = ((const half8*)b2pk)[ks2 * 256 + mt * 64 + lane];
#pragma unroll
        for (int nt = 0; nt < 4; ++nt)
            msg[nt] = __builtin_amdgcn_mfma_f32_16x16x32_f16(bf8, gf[nt], msg[nt], 0, 0, 0);
    }
    __syncthreads();   // all xsh reads done before msgred (alias) writes

    // ---- each wave writes its exclusive 16x64 tile of msgred [64][130]
#pragma unroll
    for (int nt = 0; nt < 4; ++nt)
#pragma unroll
        for (int r = 0; r < 4; ++r) {
            int i = mt * 16 + ((lane >> 4) & 3) * 4 + r;
            int e = eh * 64 + nt * 16 + (lane & 15);
            msgred[i * 130 + e] = msg[nt][r];
        }
    __syncthreads();

    // ---- scatter, coalesced: one edge row per atomic instr (lane = dim i)
#pragma unroll 1
    for (int ee = wave; ee < BE; ee += 8) {
        int d = dsts[ee];
        if (e0 + ee < N_EDGES && (unsigned)d < (unsigned)N_NODES)
            atomicAdd(agg + (size_t)d * NODE_DIM + lane, msgred[lane * 130 + ee]);
    }
}

// ---------------------------------------------------------------- phase 3
// GRUCell, transposed-LDS staging (r9, proven).
__global__ __launch_bounds__(256) void gru_kernel(
    const float* __restrict__ agg,
    const float* __restrict__ x,
    const float* __restrict__ wTih,   // [64][192]
    const float* __restrict__ wThh,   // [64][192]
    const float* __restrict__ b_ih,
    const float* __restrict__ b_hh,
    float* __restrict__ out)
{
    __shared__ float asT[4][64][12];  // [wave][k][node]
    __shared__ float xsT[4][64][12];
    const int t    = threadIdx.x;
    const int wave = t >> 6, lane = t & 63;
    const int n0   = blockIdx.x * 32;

    {
        const f32x4* asrc = (const f32x4*)(agg + (size_t)n0 * 64);
        const f32x4* xsrc = (const f32x4*)(x   + (size_t)n0 * 64);
        int nvalid4 = min(N_NODES - n0, 32) * 16;
#pragma unroll
        for (int r = 0; r < 2; ++r) {
            int idx = t + r * 256;
            f32x4 v = {0.f, 0.f, 0.f, 0.f}, u = v;
            if (idx < nvalid4) { v = asrc[idx]; u = xsrc[idx]; }
            int le = idx >> 4, q = idx & 15;
#pragma unroll
            for (int c = 0; c < 4; ++c) {
                asT[le >> 3][q * 4 + c][le & 7] = v[c];
                xsT[le >> 3][q * 4 + c][le & 7] = u[c];
            }
        }
    }
    __syncthreads();

    float accI0[8] = {}, accI1[8] = {}, accI2[8] = {};
    float accH0[8] = {}, accH1[8] = {}, accH2[8] = {};

#pragma unroll 4
    for (int k = 0; k < 64; ++k) {
        f32x4 a03 = *(const f32x4*)&asT[wave][k][0];
        f32x4 a47 = *(const f32x4*)&asT[wave][k][4];
        f32x4 x03 = *(const f32x4*)&xsT[wave][k][0];
        f32x4 x47 = *(const f32x4*)&xsT[wave][k][4];
        float wi0 = wTih[k * 192 + lane];
        float wi1 = wTih[k * 192 + 64 + lane];
        float wi2 = wTih[k * 192 + 128 + lane];
        float wh0 = wThh[k * 192 + lane];
        float wh1 = wThh[k * 192 + 64 + lane];
        float wh2 = wThh[k * 192 + 128 + lane];
#pragma unroll
        for (int n = 0; n < 8; ++n) {
            float a  = (n < 4) ? a03[n] : a47[n - 4];
            float xx = (n < 4) ? x03[n] : x47[n - 4];
            accI0[n] += a * wi0;  accI1[n] += a * wi1;  accI2[n] += a * wi2;
            accH0[n] += xx * wh0; accH1[n] += xx * wh1; accH2[n] += xx * wh2;
        }
    }

    float bi0 = b_ih[lane], bi1 = b_ih[64 + lane], bi2 = b_ih[128 + lane];
    float bh0 = b_hh[lane], bh1 = b_hh[64 + lane], bh2 = b_hh[128 + lane];
#pragma unroll
    for (int n = 0; n < 8; ++n) {
        int node = n0 + wave * 8 + n;
        if (node >= N_NODES) break;
        float r  = 1.f / (1.f + expf(-(accI0[n] + bi0 + accH0[n] + bh0)));
        float z  = 1.f / (1.f + expf(-(accI1[n] + bi1 + accH1[n] + bh1)));
        float nn = tanhf(accI2[n] + bi2 + r * (accH2[n] + bh2));
        float xv = x[(size_t)node * 64 + lane];
        out[(size_t)node * 64 + lane] = (1.f - z) * nn + z * xv;
    }
}

// ---------------------------------------------------------------- launch
extern "C" void kernel_launch(void* const* d_in, const int* in_sizes, int n_in,
                              void* d_out, int out_size, void* d_ws, size_t ws_size,
                              hipStream_t stream)
{
    const float* x          = (const float*)d_in[0];
    const int*   edge_index = (const int*)  d_in[1];
    const float* edge_attr  = (const float*)d_in[2];
    const float* W1         = (const float*)d_in[3];
    const float* b1         = (const float*)d_in[4];
    const float* W2         = (const float*)d_in[5];
    const float* b2         = (const float*)d_in[6];
    const float* w_ih       = (const float*)d_in[7];
    const float* w_hh       = (const float*)d_in[8];
    const float* b_ih       = (const float*)d_in[9];
    const float* b_hh       = (const float*)d_in[10];
    float* out = (float*)d_out;

    // ws layout: byte-identical to round 5/9 (proven; total 20,355,072 B)
    char* ws = (char*)d_ws;
    _Float16* hbuf = (_Float16*)ws;                         // 12.8 MB
    ws += (size_t)N_EDGES * HID * sizeof(_Float16);
    _Float16* Wpk  = (_Float16*)ws;                         // 1 MB
    ws += (size_t)65536 * 8 * sizeof(_Float16);
    _Float16* b2pk = (_Float16*)ws;                         // 8 KB
    ws += (size_t)512 * 8 * sizeof(_Float16);
    float* wTih = (float*)ws;                               // 48 KB
    ws += (size_t)64 * 192 * sizeof(float);
    float* wThh = (float*)ws;                               // 48 KB
    ws += (size_t)64 * 192 * sizeof(float);
    float* agg = (float*)ws;                                // 6.4 MB

    prep_kernel<<<dim3(G_MS + G_PK + G_MLP), dim3(256), 0, stream>>>(
        W2, b2, w_ih, w_hh, edge_attr, W1, b1,
        Wpk, b2pk, wTih, wThh, hbuf, agg);

    edge_msg_mfma_kernel<<<dim3((N_EDGES + BE - 1) / BE), dim3(512), 0, stream>>>(
        hbuf, x, edge_index, Wpk, b2pk, agg);

    gru_kernel<<<dim3((N_NODES + 31) / 32), dim3(256), 0, stream>>>(
        agg, x, wTih, wThh, b_ih, b_hh, out);
}

// Round 16
// 107.372 us; speedup vs baseline: 1.1404x; 1.1404x over previous
//
#include <hip/hip_runtime.h>
#include <math.h>

// EdgeConditionedConv on MI355X — round 15.
// edge_msg: r9/r5 body EXACTLY (proven 70.5us; the 4-buffer macro pipeline
// failed twice with no identified mechanism -> permanently retired).
// NEW: gru_mfma — GRU's two [64x192]x[64] matmuls on MFMA (f16 weights via
// prepacked fragments, f16 activations, f32 accum; exact-f32 x in blend).
// prep: prepack now emits gpk (GRU weight frags) instead of wT transposes;
// agg ws offset unchanged. mlp1/gather/scatter all r9-exact.

constexpr int N_NODES  = 25000;
constexpr int N_EDGES  = 50000;
constexpr int NODE_DIM = 64;
constexpr int EDGE_DIM = 16;
constexpr int HID      = 128;

typedef __attribute__((ext_vector_type(8))) _Float16 half8;
typedef __attribute__((ext_vector_type(4))) float    f32x4;

constexpr int G_MS  = 128;             // agg-zero blocks
constexpr int G_PK  = 270;             // prepack blocks (270*256 = 69120 items)
constexpr int G_MLP = N_EDGES / 8;     // mlp1 blocks (8 edges each)

// ---------------------------------------------------------------- prep
__global__ __launch_bounds__(256) void prep_kernel(
    const float* __restrict__ W2, const float* __restrict__ b2,
    const float* __restrict__ w_ih, const float* __restrict__ w_hh,
    const float* __restrict__ edge_attr, const float* __restrict__ W1,
    const float* __restrict__ b1,
    _Float16* __restrict__ Wpk, _Float16* __restrict__ b2pk,
    _Float16* __restrict__ gpk,
    _Float16* __restrict__ h, float* __restrict__ agg)
{
    int b = blockIdx.x;
    if (b < G_MS) {
        float4* a4 = (float4*)agg;
        const float4 z = make_float4(0.f, 0.f, 0.f, 0.f);
        for (int i = b * 256 + threadIdx.x; i < N_NODES * NODE_DIM / 4; i += G_MS * 256)
            a4[i] = z;
        return;
    }
    if (b < G_MS + G_PK) {
        int c = (b - G_MS) * 256 + threadIdx.x;
        if (c < 65536) {
            int lane = c & 63, mt = (c >> 6) & 3, ks = (c >> 8) & 3, j = c >> 10;
            int i   = mt * 16 + (lane & 15);
            int col = ks * 32 + ((lane >> 4) & 3) * 8;
            const float* src = W2 + (size_t)(i * 64 + j) * HID + col;
            half8 o;
#pragma unroll
            for (int q = 0; q < 8; ++q) o[q] = (_Float16)src[q];
            ((half8*)Wpk)[c] = o;
        } else if (c < 65536 + 512) {
            int c2 = c - 65536;
            int lane = c2 & 63, mt = (c2 >> 6) & 3, ks2 = (c2 >> 8) & 1;
            int i = mt * 16 + (lane & 15);
            int j = ks2 * 32 + ((lane >> 4) & 3) * 8;
            const float* src = b2 + i * 64 + j;
            half8 o;
#pragma unroll
            for (int q = 0; q < 8; ++q) o[q] = (_Float16)src[q];
            ((half8*)b2pk)[c2] = o;
        } else if (c < 65536 + 512 + 3072) {
            // GRU weight fragments: chunk c3 = ((mat*12+nt)*2+ks)*64 + lane
            int c3 = c - (65536 + 512);
            int lane = c3 & 63, ks = (c3 >> 6) & 1;
            int t2 = c3 >> 7;             // mat*12 + nt, in [0,24)
            int nt = t2 % 12, mat = t2 / 12;
            int g = nt * 16 + (lane & 15);
            int k = ks * 32 + ((lane >> 4) & 3) * 8;
            const float* src = (mat == 0 ? w_ih : w_hh) + (size_t)g * 64 + k;
            half8 o;
#pragma unroll
            for (int q = 0; q < 8; ++q) o[q] = (_Float16)src[q];
            ((half8*)gpk)[c3] = o;
        }
        return;
    }
    // mlp1: 8 edges per block (r9-exact)
    int ebase = (b - G_MS - G_PK) * 8;
    int k = threadIdx.x & 127;
    const float* w = W1 + (size_t)k * EDGE_DIM;
#pragma unroll
    for (int p = 0; p < 4; ++p) {
        int e = ebase + p * 2 + (threadIdx.x >> 7);
        if (e >= N_EDGES) break;
        const float* ea = edge_attr + (size_t)e * EDGE_DIM;
        float acc = b1[k];
#pragma unroll
        for (int d = 0; d < EDGE_DIM; ++d) acc += ea[d] * w[d];
        float g = 0.5f * acc * (1.0f + erff(acc * 0.70710678118654752f));
        h[(size_t)e * HID + k] = (_Float16)g;
    }
}

// ---------------------------------------------------------------- phase 2
// Round-5/9 body, verbatim (proven). Wave w owns output rows [w*16,w*16+16)
// for ALL j; distance-1 register prefetch of Wpk; f32 gv epilogue.
__global__ __launch_bounds__(256, 3) void edge_msg_mfma_kernel(
    const _Float16* __restrict__ hbuf,
    const float*    __restrict__ x,
    const int*      __restrict__ edge_index,   // [2][E] int32
    const _Float16* __restrict__ Wpk,
    const _Float16* __restrict__ b2pk,
    float* __restrict__ agg)                   // [N][64], pre-zeroed
{
    __shared__ float xsh[64 * 68];      // gathered x[src], pitch 68
    __shared__ float msgred[64 * 67];   // [i][e], pitch 67
    __shared__ int   dsts[64];

    const int e0   = blockIdx.x * 64;
    const int t    = threadIdx.x;
    const int mt   = t >> 6;            // wave = output row block
    const int lane = t & 63;

    // ---- gather x[src[e]] rows into xsh (zero-fill invalid) + dsts
    {
        int le = t >> 2, sub = t & 3;
        int e = e0 + le;
        int s = -1;
        if (e < N_EDGES) {
            if (sub == 0) dsts[le] = edge_index[N_EDGES + e];
            s = edge_index[e];
        } else if (sub == 0) {
            dsts[le] = -1;
        }
#pragma unroll
        for (int q = 0; q < 4; ++q) {
            float4 v = make_float4(0.f, 0.f, 0.f, 0.f);
            if ((unsigned)s < (unsigned)N_NODES)
                v = ((const float4*)x)[(size_t)s * 16 + sub * 4 + q];
            *(float4*)&xsh[le * 68 + sub * 16 + q * 4] = v;
        }
    }

    // ---- per-wave resident h fragments (B operand)
    half8 hf[4][4];   // [nt][ks]
#pragma unroll
    for (int nt = 0; nt < 4; ++nt) {
#pragma unroll
        for (int ks = 0; ks < 4; ++ks) {
            int el = nt * 16 + (lane & 15);
            int ee = e0 + el; if (ee >= N_EDGES) ee = N_EDGES - 1;
            int gk = ks * 32 + ((lane >> 4) & 3) * 8;
            hf[nt][ks] = *(const half8*)(hbuf + (size_t)ee * HID + gk);
        }
    }
    __syncthreads();

    const f32x4 zero4 = {0.f, 0.f, 0.f, 0.f};
    f32x4 msg[4];
#pragma unroll
    for (int nt = 0; nt < 4; ++nt) msg[nt] = zero4;

    const half8* wpk8 = (const half8*)Wpk;
    const int mbase = mt * 64 + lane;

    half8 aA[4], aB[4];
#pragma unroll
    for (int ks = 0; ks < 4; ++ks) aA[ks] = wpk8[(size_t)mbase + ks * 256];  // j=0

#pragma unroll 1
    for (int j = 0; j < 64; j += 2) {
        {   // prefetch j+1
            size_t nb = (size_t)(j + 1) * 1024 + mbase;
#pragma unroll
            for (int ks = 0; ks < 4; ++ks) aB[ks] = wpk8[nb + ks * 256];
        }
        {   // compute j
            float gv[4];
#pragma unroll
            for (int nt = 0; nt < 4; ++nt) gv[nt] = xsh[(nt * 16 + (lane & 15)) * 68 + j];
            f32x4 P[4];
#pragma unroll
            for (int ks = 0; ks < 4; ++ks)
#pragma unroll
                for (int nt = 0; nt < 4; ++nt)
                    P[nt] = __builtin_amdgcn_mfma_f32_16x16x32_f16(
                        aA[ks], hf[nt][ks], ks == 0 ? zero4 : P[nt], 0, 0, 0);
#pragma unroll
            for (int nt = 0; nt < 4; ++nt)
#pragma unroll
                for (int r = 0; r < 4; ++r) msg[nt][r] += gv[nt] * P[nt][r];
        }
        if (j + 2 < 64) {   // prefetch j+2
            size_t nb = (size_t)(j + 2) * 1024 + mbase;
#pragma unroll
            for (int ks = 0; ks < 4; ++ks) aA[ks] = wpk8[nb + ks * 256];
        }
        {   // compute j+1
            float gv[4];
#pragma unroll
            for (int nt = 0; nt < 4; ++nt) gv[nt] = xsh[(nt * 16 + (lane & 15)) * 68 + j + 1];
            f32x4 P[4];
#pragma unroll
            for (int ks = 0; ks < 4; ++ks)
#pragma unroll
                for (int nt = 0; nt < 4; ++nt)
                    P[nt] = __builtin_amdgcn_mfma_f32_16x16x32_f16(
                        aB[ks], hf[nt][ks], ks == 0 ? zero4 : P[nt], 0, 0, 0);
#pragma unroll
            for (int nt = 0; nt < 4; ++nt)
#pragma unroll
                for (int r = 0; r < 4; ++r) msg[nt][r] += gv[nt] * P[nt][r];
        }
    }

    // ---- bias: msg[i,e] += sum_j b2[i*64+j]*g[e,j]  (this wave's rows)
#pragma unroll
    for (int ks2 = 0; ks2 < 2; ++ks2) {
        half8 gf[4];
#pragma unroll
        for (int nt = 0; nt < 4; ++nt) {
            const float* gp = &xsh[(nt * 16 + (lane & 15)) * 68 + ks2 * 32 + ((lane >> 4) & 3) * 8];
            float4 lo = *(const float4*)gp;
            float4 hi = *(const float4*)(gp + 4);
            half8 g8;
            g8[0] = (_Float16)lo.x; g8[1] = (_Float16)lo.y;
            g8[2] = (_Float16)lo.z; g8[3] = (_Float16)lo.w;
            g8[4] = (_Float16)hi.x; g8[5] = (_Float16)hi.y;
            g8[6] = (_Float16)hi.z; g8[7] = (_Float16)hi.w;
            gf[nt] = g8;
        }
        half8 bf8 = ((const half8*)b2pk)[ks2 * 256 + mt * 64 + lane];
#pragma unroll
        for (int nt = 0; nt < 4; ++nt)
            msg[nt] = __builtin_amdgcn_mfma_f32_16x16x32_f16(bf8, gf[nt], msg[nt], 0, 0, 0);
    }

    // ---- each wave writes its exclusive 16 rows of msgred
#pragma unroll
    for (int nt = 0; nt < 4; ++nt)
#pragma unroll
        for (int r = 0; r < 4; ++r) {
            int i = mt * 16 + ((lane >> 4) & 3) * 4 + r;
            int e = nt * 16 + (lane & 15);
            msgred[i * 67 + e] = msg[nt][r];
        }
    __syncthreads();

    // ---- scatter, coalesced: one edge row per atomic instr (lane = dim i)
#pragma unroll 1
    for (int ee = mt; ee < 64; ee += 4) {
        int d = dsts[ee];
        if (e0 + ee < N_EDGES && (unsigned)d < (unsigned)N_NODES)
            atomicAdd(agg + (size_t)d * NODE_DIM + lane, msgred[lane * 67 + ee]);
    }
}

// ---------------------------------------------------------------- phase 3
// GRUCell via MFMA: 64 nodes/block (wave = 16-node m-tile). A = agg/x rows
// cast f16 in-register; B = gpk weight fragments (L2-hot, coalesced).
// C layout (validated in edge_msg): col=lane&15 -> gate, row=(lane>>4)*4+r
// -> node. Gates r/z/n live at nt=q, q+4, q+8 in the SAME lane. Blend uses
// exact f32 x. No LDS, no barriers.
__global__ __launch_bounds__(256) void gru_mfma_kernel(
    const float* __restrict__ agg,
    const float* __restrict__ x,
    const _Float16* __restrict__ gpk,
    const float* __restrict__ b_ih,
    const float* __restrict__ b_hh,
    float* __restrict__ out)
{
    const int t = threadIdx.x, wave = t >> 6, lane = t & 63;
    const int n0 = blockIdx.x * 64;

    // ---- A fragments (agg, x) for this wave's 16-node tile
    int arow = n0 + wave * 16 + (lane & 15);
    if (arow >= N_NODES) arow = N_NODES - 1;
    const int kcol = ((lane >> 4) & 3) * 8;
    half8 aF[2], xF[2];   // [ks]
#pragma unroll
    for (int ks = 0; ks < 2; ++ks) {
        const float* ap = agg + (size_t)arow * 64 + ks * 32 + kcol;
        const float* xp = x   + (size_t)arow * 64 + ks * 32 + kcol;
        float4 a0 = *(const float4*)ap, a1 = *(const float4*)(ap + 4);
        float4 x0 = *(const float4*)xp, x1 = *(const float4*)(xp + 4);
        half8 af, xf;
        af[0] = (_Float16)a0.x; af[1] = (_Float16)a0.y; af[2] = (_Float16)a0.z; af[3] = (_Float16)a0.w;
        af[4] = (_Float16)a1.x; af[5] = (_Float16)a1.y; af[6] = (_Float16)a1.z; af[7] = (_Float16)a1.w;
        xf[0] = (_Float16)x0.x; xf[1] = (_Float16)x0.y; xf[2] = (_Float16)x0.z; xf[3] = (_Float16)x0.w;
        xf[4] = (_Float16)x1.x; xf[5] = (_Float16)x1.y; xf[6] = (_Float16)x1.z; xf[7] = (_Float16)x1.w;
        aF[ks] = af; xF[ks] = xf;
    }

    const half8* g8 = (const half8*)gpk;
    const f32x4 zero4 = {0.f, 0.f, 0.f, 0.f};
    f32x4 accI[12], accH[12];
#pragma unroll
    for (int nt = 0; nt < 12; ++nt) {
        half8 b0 = g8[((0 * 12 + nt) * 2 + 0) * 64 + lane];
        half8 b1 = g8[((0 * 12 + nt) * 2 + 1) * 64 + lane];
        f32x4 a = __builtin_amdgcn_mfma_f32_16x16x32_f16(aF[0], b0, zero4, 0, 0, 0);
        accI[nt] = __builtin_amdgcn_mfma_f32_16x16x32_f16(aF[1], b1, a, 0, 0, 0);
        half8 c0 = g8[((1 * 12 + nt) * 2 + 0) * 64 + lane];
        half8 c1 = g8[((1 * 12 + nt) * 2 + 1) * 64 + lane];
        f32x4 h0 = __builtin_amdgcn_mfma_f32_16x16x32_f16(xF[0], c0, zero4, 0, 0, 0);
        accH[nt] = __builtin_amdgcn_mfma_f32_16x16x32_f16(xF[1], c1, h0, 0, 0, 0);
    }

    // ---- elementwise gates + blend (exact f32 x)
    const int nodeBase = n0 + wave * 16 + ((lane >> 4) & 3) * 4;
    const int dlo = lane & 15;
#pragma unroll
    for (int q = 0; q < 4; ++q) {
        int d = q * 16 + dlo;
        float bi0 = b_ih[d], bi1 = b_ih[64 + d], bi2 = b_ih[128 + d];
        float bh0 = b_hh[d], bh1 = b_hh[64 + d], bh2 = b_hh[128 + d];
#pragma unroll
        for (int r = 0; r < 4; ++r) {
            int node = nodeBase + r;
            if (node < N_NODES) {
                float I0 = accI[q][r] + bi0, I1 = accI[q + 4][r] + bi1, I2 = accI[q + 8][r] + bi2;
                float H0 = accH[q][r] + bh0, H1 = accH[q + 4][r] + bh1, H2 = accH[q + 8][r] + bh2;
                float rg = 1.f / (1.f + expf(-(I0 + H0)));
                float z  = 1.f / (1.f + expf(-(I1 + H1)));
                float nn = tanhf(I2 + rg * H2);
                float xv = x[(size_t)node * 64 + d];
                out[(size_t)node * 64 + d] = (1.f - z) * nn + z * xv;
            }
        }
    }
}

// ---------------------------------------------------------------- launch
extern "C" void kernel_launch(void* const* d_in, const int* in_sizes, int n_in,
                              void* d_out, int out_size, void* d_ws, size_t ws_size,
                              hipStream_t stream)
{
    const float* x          = (const float*)d_in[0];
    const int*   edge_index = (const int*)  d_in[1];
    const float* edge_attr  = (const float*)d_in[2];
    const float* W1         = (const float*)d_in[3];
    const float* b1         = (const float*)d_in[4];
    const float* W2         = (const float*)d_in[5];
    const float* b2         = (const float*)d_in[6];
    const float* w_ih       = (const float*)d_in[7];
    const float* w_hh       = (const float*)d_in[8];
    const float* b_ih       = (const float*)d_in[9];
    const float* b_hh       = (const float*)d_in[10];
    float* out = (float*)d_out;

    // ws layout: identical offsets to round 5/9 (proven; total 20,355,072 B).
    // gpk (49,152 B) lives inside the old wTih slot; agg offset UNCHANGED.
    char* ws = (char*)d_ws;
    _Float16* hbuf = (_Float16*)ws;                         // 12.8 MB
    ws += (size_t)N_EDGES * HID * sizeof(_Float16);
    _Float16* Wpk  = (_Float16*)ws;                         // 1 MB
    ws += (size_t)65536 * 8 * sizeof(_Float16);
    _Float16* b2pk = (_Float16*)ws;                         // 8 KB
    ws += (size_t)512 * 8 * sizeof(_Float16);
    _Float16* gpk  = (_Float16*)ws;                         // 48 KB slot (uses 49,152 B? no: 3072*16B = 49,152 B) -> spans into next slot
    ws += (size_t)64 * 192 * sizeof(float);                 // 48 KB
    ws += (size_t)64 * 192 * sizeof(float);                 // 48 KB (gpk uses 49,152 of these 98,304 B)
    float* agg = (float*)ws;                                // 6.4 MB (same offset as r5/r9)

    prep_kernel<<<dim3(G_MS + G_PK + G_MLP), dim3(256), 0, stream>>>(
        W2, b2, w_ih, w_hh, edge_attr, W1, b1,
        Wpk, b2pk, gpk, hbuf, agg);

    edge_msg_mfma_kernel<<<dim3((N_EDGES + 63) / 64), dim3(256), 0, stream>>>(
        hbuf, x, edge_index, Wpk, b2pk, agg);

    gru_mfma_kernel<<<dim3((N_NODES + 63) / 64), dim3(256), 0, stream>>>(
        agg, x, gpk, b_ih, b_hh, out);
}

// Round 17
// 100.394 us; speedup vs baseline: 1.2197x; 1.0695x over previous
//
#include <hip/hip_runtime.h>
#include <math.h>

// EdgeConditionedConv on MI355X — round 16: fuse mlp1 into edge_msg.
// Each block computes h for its own 64 edges in-LDS (hsh aliases msgred,
// dead until post-loop; W1 staged with broadcast reads). Removes the
// 12.8MB hbuf write+read round-trip and ~94% of prep's grid. h math is
// bit-identical to mlp1 (same FMA order, gelu, f16 cast).
// edge_msg j-loop / scatter = r9-proven; gru_mfma = r15-proven.

constexpr int N_NODES  = 25000;
constexpr int N_EDGES  = 50000;
constexpr int NODE_DIM = 64;
constexpr int EDGE_DIM = 16;
constexpr int HID      = 128;

typedef __attribute__((ext_vector_type(8))) _Float16 half8;
typedef __attribute__((ext_vector_type(4))) float    f32x4;

constexpr int G_MS  = 128;             // agg-zero blocks
constexpr int G_PK  = 270;             // prepack blocks (270*256 = 69120 items)

// ---------------------------------------------------------------- prep
__global__ __launch_bounds__(256) void prep_kernel(
    const float* __restrict__ W2, const float* __restrict__ b2,
    const float* __restrict__ w_ih, const float* __restrict__ w_hh,
    _Float16* __restrict__ Wpk, _Float16* __restrict__ b2pk,
    _Float16* __restrict__ gpk, float* __restrict__ agg)
{
    int b = blockIdx.x;
    if (b < G_MS) {
        float4* a4 = (float4*)agg;
        const float4 z = make_float4(0.f, 0.f, 0.f, 0.f);
        for (int i = b * 256 + threadIdx.x; i < N_NODES * NODE_DIM / 4; i += G_MS * 256)
            a4[i] = z;
        return;
    }
    int c = (b - G_MS) * 256 + threadIdx.x;
    if (c < 65536) {
        int lane = c & 63, mt = (c >> 6) & 3, ks = (c >> 8) & 3, j = c >> 10;
        int i   = mt * 16 + (lane & 15);
        int col = ks * 32 + ((lane >> 4) & 3) * 8;
        const float* src = W2 + (size_t)(i * 64 + j) * HID + col;
        half8 o;
#pragma unroll
        for (int q = 0; q < 8; ++q) o[q] = (_Float16)src[q];
        ((half8*)Wpk)[c] = o;
    } else if (c < 65536 + 512) {
        int c2 = c - 65536;
        int lane = c2 & 63, mt = (c2 >> 6) & 3, ks2 = (c2 >> 8) & 1;
        int i = mt * 16 + (lane & 15);
        int j = ks2 * 32 + ((lane >> 4) & 3) * 8;
        const float* src = b2 + i * 64 + j;
        half8 o;
#pragma unroll
        for (int q = 0; q < 8; ++q) o[q] = (_Float16)src[q];
        ((half8*)b2pk)[c2] = o;
    } else if (c < 65536 + 512 + 3072) {
        // GRU weight fragments: chunk c3 = ((mat*12+nt)*2+ks)*64 + lane
        int c3 = c - (65536 + 512);
        int lane = c3 & 63, ks = (c3 >> 6) & 1;
        int t2 = c3 >> 7;             // mat*12 + nt, in [0,24)
        int nt = t2 % 12, mat = t2 / 12;
        int g = nt * 16 + (lane & 15);
        int k = ks * 32 + ((lane >> 4) & 3) * 8;
        const float* src = (mat == 0 ? w_ih : w_hh) + (size_t)g * 64 + k;
        half8 o;
#pragma unroll
        for (int q = 0; q < 8; ++q) o[q] = (_Float16)src[q];
        ((half8*)gpk)[c3] = o;
    }
}

// ---------------------------------------------------------------- phase 2
// r9-proven j-loop + in-block mlp1. Wave w owns output rows [w*16,w*16+16)
// for ALL j; distance-1 register prefetch of Wpk; f32 gv epilogue.
__global__ __launch_bounds__(256, 3) void edge_msg_mfma_kernel(
    const float*    __restrict__ edge_attr,
    const float*    __restrict__ W1,
    const float*    __restrict__ b1,
    const float*    __restrict__ x,
    const int*      __restrict__ edge_index,   // [2][E] int32
    const _Float16* __restrict__ Wpk,
    const _Float16* __restrict__ b2pk,
    float* __restrict__ agg)                   // [N][64], pre-zeroed
{
    __shared__ float xsh[64 * 68];      // gathered x[src], pitch 68 (17408 B)
    __shared__ float msgred[64 * 67];   // [i][e], pitch 67 (17152 B)
    __shared__ float W1s[128 * 16];     // 8192 B
    __shared__ float b1s[128];
    __shared__ int   dsts[64];
    _Float16* hsh = (_Float16*)msgred;  // alias: [64][128] f16 (16384 B), dead before msgred use

    const int e0   = blockIdx.x * 64;
    const int t    = threadIdx.x;
    const int mt   = t >> 6;            // wave = output row block
    const int lane = t & 63;

    // ---- gather x[src[e]] rows into xsh (zero-fill invalid) + dsts
    {
        int le = t >> 2, sub = t & 3;
        int e = e0 + le;
        int s = -1;
        if (e < N_EDGES) {
            if (sub == 0) dsts[le] = edge_index[N_EDGES + e];
            s = edge_index[e];
        } else if (sub == 0) {
            dsts[le] = -1;
        }
#pragma unroll
        for (int q = 0; q < 4; ++q) {
            float4 v = make_float4(0.f, 0.f, 0.f, 0.f);
            if ((unsigned)s < (unsigned)N_NODES)
                v = ((const float4*)x)[(size_t)s * 16 + sub * 4 + q];
            *(float4*)&xsh[le * 68 + sub * 16 + q * 4] = v;
        }
    }

    // ---- stage W1/b1
#pragma unroll
    for (int r = 0; r < 8; ++r) W1s[t + r * 256] = W1[t + r * 256];
    if (t < 128) b1s[t] = b1[t];
    __syncthreads();

    // ---- in-block mlp1: h[le][k] = gelu(ea . W1[k] + b1[k]) -> hsh (f16)
    {
        int le = t >> 2, sub = t & 3;
        int e = e0 + le;
        float ea[16];
        if (e < N_EDGES) {
            const float4* ea4 = (const float4*)(edge_attr + (size_t)e * EDGE_DIM);
#pragma unroll
            for (int q = 0; q < 4; ++q) {
                float4 v = ea4[q];
                ea[q * 4] = v.x; ea[q * 4 + 1] = v.y; ea[q * 4 + 2] = v.z; ea[q * 4 + 3] = v.w;
            }
        } else {
#pragma unroll
            for (int d = 0; d < 16; ++d) ea[d] = 0.f;
        }
#pragma unroll
        for (int kc = 0; kc < 4; ++kc) {      // 4 chunks of 8 k-values
            half8 hh;
#pragma unroll
            for (int kk = 0; kk < 8; ++kk) {
                int k = sub * 32 + kc * 8 + kk;
                float acc = b1s[k];
                const float* w = &W1s[k * 16];
#pragma unroll
                for (int d = 0; d < EDGE_DIM; ++d) acc += ea[d] * w[d];
                float g = 0.5f * acc * (1.0f + erff(acc * 0.70710678118654752f));
                hh[kk] = (_Float16)g;
            }
            *(half8*)&hsh[le * 128 + sub * 32 + kc * 8] = hh;
        }
    }
    __syncthreads();

    // ---- per-wave resident h fragments (B operand) from hsh
    half8 hf[4][4];   // [nt][ks]
#pragma unroll
    for (int nt = 0; nt < 4; ++nt) {
#pragma unroll
        for (int ks = 0; ks < 4; ++ks) {
            int el = nt * 16 + (lane & 15);
            int gk = ks * 32 + ((lane >> 4) & 3) * 8;
            hf[nt][ks] = *(const half8*)&hsh[el * 128 + gk];
        }
    }
    __syncthreads();   // hsh dead after this point (msgred may overwrite)

    const f32x4 zero4 = {0.f, 0.f, 0.f, 0.f};
    f32x4 msg[4];
#pragma unroll
    for (int nt = 0; nt < 4; ++nt) msg[nt] = zero4;

    const half8* wpk8 = (const half8*)Wpk;
    const int mbase = mt * 64 + lane;

    half8 aA[4], aB[4];
#pragma unroll
    for (int ks = 0; ks < 4; ++ks) aA[ks] = wpk8[(size_t)mbase + ks * 256];  // j=0

#pragma unroll 1
    for (int j = 0; j < 64; j += 2) {
        {   // prefetch j+1
            size_t nb = (size_t)(j + 1) * 1024 + mbase;
#pragma unroll
            for (int ks = 0; ks < 4; ++ks) aB[ks] = wpk8[nb + ks * 256];
        }
        {   // compute j
            float gv[4];
#pragma unroll
            for (int nt = 0; nt < 4; ++nt) gv[nt] = xsh[(nt * 16 + (lane & 15)) * 68 + j];
            f32x4 P[4];
#pragma unroll
            for (int ks = 0; ks < 4; ++ks)
#pragma unroll
                for (int nt = 0; nt < 4; ++nt)
                    P[nt] = __builtin_amdgcn_mfma_f32_16x16x32_f16(
                        aA[ks], hf[nt][ks], ks == 0 ? zero4 : P[nt], 0, 0, 0);
#pragma unroll
            for (int nt = 0; nt < 4; ++nt)
#pragma unroll
                for (int r = 0; r < 4; ++r) msg[nt][r] += gv[nt] * P[nt][r];
        }
        if (j + 2 < 64) {   // prefetch j+2
            size_t nb = (size_t)(j + 2) * 1024 + mbase;
#pragma unroll
            for (int ks = 0; ks < 4; ++ks) aA[ks] = wpk8[nb + ks * 256];
        }
        {   // compute j+1
            float gv[4];
#pragma unroll
            for (int nt = 0; nt < 4; ++nt) gv[nt] = xsh[(nt * 16 + (lane & 15)) * 68 + j + 1];
            f32x4 P[4];
#pragma unroll
            for (int ks = 0; ks < 4; ++ks)
#pragma unroll
                for (int nt = 0; nt < 4; ++nt)
                    P[nt] = __builtin_amdgcn_mfma_f32_16x16x32_f16(
                        aB[ks], hf[nt][ks], ks == 0 ? zero4 : P[nt], 0, 0, 0);
#pragma unroll
            for (int nt = 0; nt < 4; ++nt)
#pragma unroll
                for (int r = 0; r < 4; ++r) msg[nt][r] += gv[nt] * P[nt][r];
        }
    }

    // ---- bias: msg[i,e] += sum_j b2[i*64+j]*g[e,j]  (this wave's rows)
#pragma unroll
    for (int ks2 = 0; ks2 < 2; ++ks2) {
        half8 gf[4];
#pragma unroll
        for (int nt = 0; nt < 4; ++nt) {
            const float* gp = &xsh[(nt * 16 + (lane & 15)) * 68 + ks2 * 32 + ((lane >> 4) & 3) * 8];
            float4 lo = *(const float4*)gp;
            float4 hi = *(const float4*)(gp + 4);
            half8 g8;
            g8[0] = (_Float16)lo.x; g8[1] = (_Float16)lo.y;
            g8[2] = (_Float16)lo.z; g8[3] = (_Float16)lo.w;
            g8[4] = (_Float16)hi.x; g8[5] = (_Float16)hi.y;
            g8[6] = (_Float16)hi.z; g8[7] = (_Float16)hi.w;
            gf[nt] = g8;
        }
        half8 bf8 = ((const half8*)b2pk)[ks2 * 256 + mt * 64 + lane];
#pragma unroll
        for (int nt = 0; nt < 4; ++nt)
            msg[nt] = __builtin_amdgcn_mfma_f32_16x16x32_f16(bf8, gf[nt], msg[nt], 0, 0, 0);
    }

    // ---- each wave writes its exclusive 16 rows of msgred
#pragma unroll
    for (int nt = 0; nt < 4; ++nt)
#pragma unroll
        for (int r = 0; r < 4; ++r) {
            int i = mt * 16 + ((lane >> 4) & 3) * 4 + r;
            int e = nt * 16 + (lane & 15);
            msgred[i * 67 + e] = msg[nt][r];
        }
    __syncthreads();

    // ---- scatter, coalesced: one edge row per atomic instr (lane = dim i)
#pragma unroll 1
    for (int ee = mt; ee < 64; ee += 4) {
        int d = dsts[ee];
        if (e0 + ee < N_EDGES && (unsigned)d < (unsigned)N_NODES)
            atomicAdd(agg + (size_t)d * NODE_DIM + lane, msgred[lane * 67 + ee]);
    }
}

// ---------------------------------------------------------------- phase 3
// GRUCell via MFMA (r15-proven).
__global__ __launch_bounds__(256) void gru_mfma_kernel(
    const float* __restrict__ agg,
    const float* __restrict__ x,
    const _Float16* __restrict__ gpk,
    const float* __restrict__ b_ih,
    const float* __restrict__ b_hh,
    float* __restrict__ out)
{
    const int t = threadIdx.x, wave = t >> 6, lane = t & 63;
    const int n0 = blockIdx.x * 64;

    int arow = n0 + wave * 16 + (lane & 15);
    if (arow >= N_NODES) arow = N_NODES - 1;
    const int kcol = ((lane >> 4) & 3) * 8;
    half8 aF[2], xF[2];   // [ks]
#pragma unroll
    for (int ks = 0; ks < 2; ++ks) {
        const float* ap = agg + (size_t)arow * 64 + ks * 32 + kcol;
        const float* xp = x   + (size_t)arow * 64 + ks * 32 + kcol;
        float4 a0 = *(const float4*)ap, a1 = *(const float4*)(ap + 4);
        float4 x0 = *(const float4*)xp, x1 = *(const float4*)(xp + 4);
        half8 af, xf;
        af[0] = (_Float16)a0.x; af[1] = (_Float16)a0.y; af[2] = (_Float16)a0.z; af[3] = (_Float16)a0.w;
        af[4] = (_Float16)a1.x; af[5] = (_Float16)a1.y; af[6] = (_Float16)a1.z; af[7] = (_Float16)a1.w;
        xf[0] = (_Float16)x0.x; xf[1] = (_Float16)x0.y; xf[2] = (_Float16)x0.z; xf[3] = (_Float16)x0.w;
        xf[4] = (_Float16)x1.x; xf[5] = (_Float16)x1.y; xf[6] = (_Float16)x1.z; xf[7] = (_Float16)x1.w;
        aF[ks] = af; xF[ks] = xf;
    }

    const half8* g8 = (const half8*)gpk;
    const f32x4 zero4 = {0.f, 0.f, 0.f, 0.f};
    f32x4 accI[12], accH[12];
#pragma unroll
    for (int nt = 0; nt < 12; ++nt) {
        half8 b0 = g8[((0 * 12 + nt) * 2 + 0) * 64 + lane];
        half8 b1f = g8[((0 * 12 + nt) * 2 + 1) * 64 + lane];
        f32x4 a = __builtin_amdgcn_mfma_f32_16x16x32_f16(aF[0], b0, zero4, 0, 0, 0);
        accI[nt] = __builtin_amdgcn_mfma_f32_16x16x32_f16(aF[1], b1f, a, 0, 0, 0);
        half8 c0 = g8[((1 * 12 + nt) * 2 + 0) * 64 + lane];
        half8 c1 = g8[((1 * 12 + nt) * 2 + 1) * 64 + lane];
        f32x4 h0 = __builtin_amdgcn_mfma_f32_16x16x32_f16(xF[0], c0, zero4, 0, 0, 0);
        accH[nt] = __builtin_amdgcn_mfma_f32_16x16x32_f16(xF[1], c1, h0, 0, 0, 0);
    }

    const int nodeBase = n0 + wave * 16 + ((lane >> 4) & 3) * 4;
    const int dlo = lane & 15;
#pragma unroll
    for (int q = 0; q < 4; ++q) {
        int d = q * 16 + dlo;
        float bi0 = b_ih[d], bi1 = b_ih[64 + d], bi2 = b_ih[128 + d];
        float bh0 = b_hh[d], bh1 = b_hh[64 + d], bh2 = b_hh[128 + d];
#pragma unroll
        for (int r = 0; r < 4; ++r) {
            int node = nodeBase + r;
            if (node < N_NODES) {
                float I0 = accI[q][r] + bi0, I1 = accI[q + 4][r] + bi1, I2 = accI[q + 8][r] + bi2;
                float H0 = accH[q][r] + bh0, H1 = accH[q + 4][r] + bh1, H2 = accH[q + 8][r] + bh2;
                float rg = 1.f / (1.f + expf(-(I0 + H0)));
                float z  = 1.f / (1.f + expf(-(I1 + H1)));
                float nn = tanhf(I2 + rg * H2);
                float xv = x[(size_t)node * 64 + d];
                out[(size_t)node * 64 + d] = (1.f - z) * nn + z * xv;
            }
        }
    }
}

// ---------------------------------------------------------------- launch
extern "C" void kernel_launch(void* const* d_in, const int* in_sizes, int n_in,
                              void* d_out, int out_size, void* d_ws, size_t ws_size,
                              hipStream_t stream)
{
    const float* x          = (const float*)d_in[0];
    const int*   edge_index = (const int*)  d_in[1];
    const float* edge_attr  = (const float*)d_in[2];
    const float* W1         = (const float*)d_in[3];
    const float* b1         = (const float*)d_in[4];
    const float* W2         = (const float*)d_in[5];
    const float* b2         = (const float*)d_in[6];
    const float* w_ih       = (const float*)d_in[7];
    const float* w_hh       = (const float*)d_in[8];
    const float* b_ih       = (const float*)d_in[9];
    const float* b_hh       = (const float*)d_in[10];
    float* out = (float*)d_out;

    // ws layout: identical offsets to round 5/9/15 (proven; 20,355,072 B).
    // hbuf slot now unused (h fused in-block); offsets intentionally kept.
    char* ws = (char*)d_ws;
    ws += (size_t)N_EDGES * HID * sizeof(_Float16);         // (unused hbuf slot, 12.8 MB)
    _Float16* Wpk  = (_Float16*)ws;                         // 1 MB
    ws += (size_t)65536 * 8 * sizeof(_Float16);
    _Float16* b2pk = (_Float16*)ws;                         // 8 KB
    ws += (size_t)512 * 8 * sizeof(_Float16);
    _Float16* gpk  = (_Float16*)ws;                         // 49,152 B within the two 48 KB slots
    ws += (size_t)64 * 192 * sizeof(float);                 // 48 KB
    ws += (size_t)64 * 192 * sizeof(float);                 // 48 KB
    float* agg = (float*)ws;                                // 6.4 MB (same offset as r5/r9/r15)

    prep_kernel<<<dim3(G_MS + G_PK), dim3(256), 0, stream>>>(
        W2, b2, w_ih, w_hh, Wpk, b2pk, gpk, agg);

    edge_msg_mfma_kernel<<<dim3((N_EDGES + 63) / 64), dim3(256), 0, stream>>>(
        edge_attr, W1, b1, x, edge_index, Wpk, b2pk, agg);

    gru_mfma_kernel<<<dim3((N_NODES + 63) / 64), dim3(256), 0, stream>>>(
        agg, x, gpk, b_ih, b_hh, out);
}